// Round 1
// baseline (1504.544 us; speedup 1.0000x reference)
//
#include <hip/hip_runtime.h>
#include <math.h>

#define NN   100000
#define HH   128
#define EXTD 768
#define EE   1600000
#define LNEPS 1e-5f

#define BK   32
#define LSTR 132   // LDS row stride (128 + 4 pad)

// ---------------- CSR build ----------------

__global__ void k_init(int* __restrict__ deg, int* __restrict__ counter) {
    int i = blockIdx.x * 256 + threadIdx.x;
    if (i < NN) deg[i] = 1;            // self loop contributes 1 to degree
    if (i == 0) *counter = 0;
}

__global__ void k_count(const int* __restrict__ dst, int* __restrict__ deg) {
    int e = blockIdx.x * 256 + threadIdx.x;
    if (e < EE) atomicAdd(&deg[dst[e]], 1);
}

__global__ void k_offsets(const int* __restrict__ deg, float* __restrict__ dinv,
                          int* __restrict__ rowstart, int* __restrict__ cursor,
                          int* __restrict__ counter) {
    int i = blockIdx.x * 256 + threadIdx.x;
    if (i < NN) {
        int d = deg[i];
        dinv[i] = rsqrtf((float)d);
        int rs = atomicAdd(counter, d - 1);   // in-degree excluding self loop
        rowstart[i] = rs;
        cursor[i]   = rs;
    }
}

__global__ void k_fill(const int* __restrict__ src, const int* __restrict__ dst,
                       int* __restrict__ cursor, int* __restrict__ col) {
    int e = blockIdx.x * 256 + threadIdx.x;
    if (e < EE) {
        int d = dst[e];
        int p = atomicAdd(&cursor[d], 1);
        col[p] = src[e];
    }
}

// ---------------- GEMM: C[N x 128] = A[N x K] @ W[K x 128] (+bias)(+LN+ReLU)(+rowscale) ----
// 128x128 block, 256 threads, 8x8 per-thread tile.
// A-frag LDS reads are 16-lane broadcasts (depend on ty only); B-frag reads are
// 4-lane broadcasts -> unique LDS bytes/wave/k is small -> VALU-bound.

template<int LNRELU, int CONCAT, int ROWSCALE>
__global__ __launch_bounds__(256, 4)
void k_gemm(const float* __restrict__ A0, const float* __restrict__ A1,
            const float* __restrict__ W,  const float* __restrict__ bias,
            const float* __restrict__ lng, const float* __restrict__ lnb,
            const float* __restrict__ rowscale,
            float* __restrict__ C, int K)
{
    __shared__ float As[BK * LSTR];   // [k][row]
    __shared__ float Bs[BK * LSTR];   // [k][col]

    const int tid  = threadIdx.x;
    const int tx   = tid & 15;         // col group (8 cols)
    const int ty   = tid >> 4;         // row group (8 rows)
    const int row0 = blockIdx.x * 128;

    // A staging: thread covers row ar, 16 consecutive k-floats starting at ah
    const int ar    = tid >> 1;          // 0..127
    const int ah    = (tid & 1) * 16;    // 0 or 16
    const int garow = row0 + ar;

    // B staging: thread loads 4 float4: k rows bkr, bkr+8, bkr+16, bkr+24; cols bc..bc+3
    const int bkr = tid >> 5;            // 0..7
    const int bc  = (tid & 31) * 4;      // 0..124

    float acc[8][8];
#pragma unroll
    for (int i = 0; i < 8; ++i)
#pragma unroll
        for (int j = 0; j < 8; ++j) acc[i][j] = 0.f;

    for (int k0 = 0; k0 < K; k0 += BK) {
        float4 a_ld[2] = {make_float4(0.f,0.f,0.f,0.f), make_float4(0.f,0.f,0.f,0.f)};
        float4 a_ld2[2] = {make_float4(0.f,0.f,0.f,0.f), make_float4(0.f,0.f,0.f,0.f)};
        if (garow < NN) {
            const float* ap;
            if (CONCAT) {
                ap = (k0 < HH) ? (A0 + (size_t)garow * HH + k0)
                               : (A1 + (size_t)garow * HH + (k0 - HH));
            } else {
                ap = A0 + (size_t)garow * K + k0;
            }
            a_ld[0]  = *(const float4*)(ap + ah + 0);
            a_ld[1]  = *(const float4*)(ap + ah + 4);
            a_ld2[0] = *(const float4*)(ap + ah + 8);
            a_ld2[1] = *(const float4*)(ap + ah + 12);
        }
        float4 b_ld[4];
#pragma unroll
        for (int p = 0; p < 4; ++p)
            b_ld[p] = *(const float4*)(W + (size_t)(k0 + bkr + p * 8) * 128 + bc);

        __syncthreads();
        {
            const float av[16] = {a_ld[0].x, a_ld[0].y, a_ld[0].z, a_ld[0].w,
                                  a_ld[1].x, a_ld[1].y, a_ld[1].z, a_ld[1].w,
                                  a_ld2[0].x, a_ld2[0].y, a_ld2[0].z, a_ld2[0].w,
                                  a_ld2[1].x, a_ld2[1].y, a_ld2[1].z, a_ld2[1].w};
#pragma unroll
            for (int m = 0; m < 16; ++m)
                As[(ah + m) * LSTR + ar] = av[m];
#pragma unroll
            for (int p = 0; p < 4; ++p)
                *(float4*)&Bs[(bkr + p * 8) * LSTR + bc] = b_ld[p];
        }
        __syncthreads();

#pragma unroll 4
        for (int k = 0; k < BK; ++k) {
            const float4 a0 = *(const float4*)&As[k * LSTR + ty * 8];
            const float4 a1 = *(const float4*)&As[k * LSTR + ty * 8 + 4];
            const float4 b0 = *(const float4*)&Bs[k * LSTR + tx * 8];
            const float4 b1 = *(const float4*)&Bs[k * LSTR + tx * 8 + 4];
            const float av[8] = {a0.x, a0.y, a0.z, a0.w, a1.x, a1.y, a1.z, a1.w};
            const float bv[8] = {b0.x, b0.y, b0.z, b0.w, b1.x, b1.y, b1.z, b1.w};
#pragma unroll
            for (int i = 0; i < 8; ++i)
#pragma unroll
                for (int j = 0; j < 8; ++j)
                    acc[i][j] = fmaf(av[i], bv[j], acc[i][j]);
        }
    }

    const int c0 = tx * 8;

    if (bias != nullptr) {
        const float4 q0 = *(const float4*)&bias[c0];
        const float4 q1 = *(const float4*)&bias[c0 + 4];
        const float qb[8] = {q0.x, q0.y, q0.z, q0.w, q1.x, q1.y, q1.z, q1.w};
#pragma unroll
        for (int i = 0; i < 8; ++i)
#pragma unroll
            for (int j = 0; j < 8; ++j) acc[i][j] += qb[j];
    }

    if constexpr (LNRELU) {
        // per-row reduce across the 16 tx lanes (consecutive lanes, xor shuffles)
        const float4 g0 = *(const float4*)&lng[c0];
        const float4 g1 = *(const float4*)&lng[c0 + 4];
        const float4 h0 = *(const float4*)&lnb[c0];
        const float4 h1 = *(const float4*)&lnb[c0 + 4];
        const float gg[8] = {g0.x, g0.y, g0.z, g0.w, g1.x, g1.y, g1.z, g1.w};
        const float hh[8] = {h0.x, h0.y, h0.z, h0.w, h1.x, h1.y, h1.z, h1.w};
#pragma unroll
        for (int i = 0; i < 8; ++i) {
            float s1 = 0.f, s2 = 0.f;
#pragma unroll
            for (int j = 0; j < 8; ++j) { s1 += acc[i][j]; s2 = fmaf(acc[i][j], acc[i][j], s2); }
#pragma unroll
            for (int m = 1; m < 16; m <<= 1) {
                s1 += __shfl_xor(s1, m);
                s2 += __shfl_xor(s2, m);
            }
            const float mu  = s1 * (1.0f / HH);
            const float var = fmaf(-mu, mu, s2 * (1.0f / HH));
            const float rsd = rsqrtf(var + LNEPS);
#pragma unroll
            for (int j = 0; j < 8; ++j) {
                float v = (acc[i][j] - mu) * rsd;
                v = fmaf(v, gg[j], hh[j]);
                acc[i][j] = fmaxf(v, 0.f);
            }
        }
    }

    if constexpr (ROWSCALE) {
#pragma unroll
        for (int i = 0; i < 8; ++i) {
            const int r = row0 + ty * 8 + i;
            const float sc = (r < NN) ? rowscale[r] : 0.f;
#pragma unroll
            for (int j = 0; j < 8; ++j) acc[i][j] *= sc;
        }
    }

#pragma unroll
    for (int i = 0; i < 8; ++i) {
        const int r = row0 + ty * 8 + i;
        if (r < NN) {
            float* cp = C + (size_t)r * 128 + c0;
            *(float4*)(cp)     = make_float4(acc[i][0], acc[i][1], acc[i][2], acc[i][3]);
            *(float4*)(cp + 4) = make_float4(acc[i][4], acc[i][5], acc[i][6], acc[i][7]);
        }
    }
}

// ---------------- SpMM: out[d] = dinv[d]*(sum Z[src] + Z[d]) + bias, Z pre-scaled by dinv ----
// One wave per destination node; lane owns 2 channels. x8 unroll: 8 independent
// 512B row gathers in flight; col[] reads are wave-uniform (scalar path).

__global__ __launch_bounds__(256)
void k_spmm(const float* __restrict__ Z, const int* __restrict__ col,
            const int* __restrict__ rs, const int* __restrict__ re,
            const float* __restrict__ dinv, const float* __restrict__ bias,
            float* __restrict__ out, int dorelu)
{
    int gid  = blockIdx.x * blockDim.x + threadIdx.x;
    int node = gid >> 6;
    int lane = threadIdx.x & 63;
    if (node >= NN) return;

    const int beg = rs[node];
    const int end = re[node];
    const float di = dinv[node];
    const size_t lofs = (size_t)(lane * 2);

    float ax, ay;
    {   // self loop: Z[d] already = dinv[d]*Y[d]
        const float2 v = *(const float2*)(Z + (size_t)node * HH + lofs);
        ax = v.x;
        ay = v.y;
    }

    int e = beg;
    const int e8 = beg + ((end - beg) & ~7);
    for (; e < e8; e += 8) {
        int s[8];
#pragma unroll
        for (int q = 0; q < 8; ++q) s[q] = col[e + q];
        float2 v[8];
#pragma unroll
        for (int q = 0; q < 8; ++q)
            v[q] = *(const float2*)(Z + (size_t)s[q] * HH + lofs);
#pragma unroll
        for (int q = 0; q < 8; ++q) { ax += v[q].x; ay += v[q].y; }
    }
    for (; e < end; ++e) {
        const int s0 = col[e];
        const float2 v = *(const float2*)(Z + (size_t)s0 * HH + lofs);
        ax += v.x;
        ay += v.y;
    }

    float ox = fmaf(di, ax, bias[lane * 2]);
    float oy = fmaf(di, ay, bias[lane * 2 + 1]);
    if (dorelu) { ox = fmaxf(ox, 0.f); oy = fmaxf(oy, 0.f); }
    float2 o; o.x = ox; o.y = oy;
    *(float2*)(out + (size_t)node * HH + lofs) = o;
}

// ---------------- launch ----------------

extern "C" void kernel_launch(void* const* d_in, const int* in_sizes, int n_in,
                              void* d_out, int out_size, void* d_ws, size_t ws_size,
                              hipStream_t stream)
{
    const int*   ei    = (const int*)d_in[0];
    const float* ext   = (const float*)d_in[1];
    const float* emb   = (const float*)d_in[2];
    const float* encW  = (const float*)d_in[3];
    const float* encB  = (const float*)d_in[4];
    const float* lng   = (const float*)d_in[5];
    const float* lnb   = (const float*)d_in[6];
    const float* projW = (const float*)d_in[7];
    const float* projB = (const float*)d_in[8];
    const float* W0    = (const float*)d_in[9];
    const float* b0    = (const float*)d_in[10];
    const float* W1    = (const float*)d_in[11];
    const float* b1    = (const float*)d_in[12];
    const float* W2    = (const float*)d_in[13];
    const float* b2    = (const float*)d_in[14];

    const int* srcI = ei;        // edge_index[0]
    const int* dstI = ei + EE;   // edge_index[1]

    char* w = (char*)d_ws;
    size_t off = 0;
    auto alloc = [&](size_t bytes) -> void* {
        void* p = w + off;
        off += (bytes + 255) & ~(size_t)255;
        return p;
    };
    int*   deg      = (int*)alloc((size_t)NN * 4);
    float* dinv     = (float*)alloc((size_t)NN * 4);
    int*   rowstart = (int*)alloc((size_t)NN * 4);
    int*   cursor   = (int*)alloc((size_t)NN * 4);
    int*   counter  = (int*)alloc(256);
    int*   col      = (int*)alloc((size_t)EE * 4);
    float* bufA     = (float*)alloc((size_t)NN * HH * 4);
    float* bufB     = (float*)alloc((size_t)NN * HH * 4);

    const int gN = (NN + 255) / 256;
    const int gE = (EE + 255) / 256;
    const int gG = (NN + 127) / 128;   // 128 rows per block
    const int gS = (NN + 3) / 4;       // 4 waves (nodes) per 256-thread block

    k_init   <<<gN, 256, 0, stream>>>(deg, counter);
    k_count  <<<gE, 256, 0, stream>>>(dstI, deg);
    k_offsets<<<gN, 256, 0, stream>>>(deg, dinv, rowstart, cursor, counter);
    k_fill   <<<gE, 256, 0, stream>>>(srcI, dstI, cursor, col);

    // feat = relu(LN(ext @ encW + encB))                    -> bufA
    k_gemm<1, 0, 0><<<gG, 256, 0, stream>>>(ext, nullptr, encW, encB, lng, lnb, nullptr, bufA, EXTD);
    // x = concat(emb, feat) @ projW + projB                 -> bufB
    k_gemm<0, 1, 0><<<gG, 256, 0, stream>>>(emb, bufA, projW, projB, nullptr, nullptr, nullptr, bufB, 2 * HH);
    // Z0 = dinv .* (x @ W0)                                 -> bufA
    k_gemm<0, 0, 1><<<gG, 256, 0, stream>>>(bufB, nullptr, W0, nullptr, nullptr, nullptr, dinv, bufA, HH);
    // x = relu(dinv.*(sum Z0) + b0)                         -> bufB
    k_spmm<<<gS, 256, 0, stream>>>(bufA, col, rowstart, cursor, dinv, b0, bufB, 1);
    // Z1 = dinv .* (x @ W1)                                 -> bufA
    k_gemm<0, 0, 1><<<gG, 256, 0, stream>>>(bufB, nullptr, W1, nullptr, nullptr, nullptr, dinv, bufA, HH);
    // x = relu(dinv.*(sum Z1) + b1)                         -> bufB
    k_spmm<<<gS, 256, 0, stream>>>(bufA, col, rowstart, cursor, dinv, b1, bufB, 1);
    // Z2 = dinv .* (x @ W2)                                 -> bufA
    k_gemm<0, 0, 1><<<gG, 256, 0, stream>>>(bufB, nullptr, W2, nullptr, nullptr, nullptr, dinv, bufA, HH);
    // out = dinv.*(sum Z2) + b2                             -> d_out
    k_spmm<<<gS, 256, 0, stream>>>(bufA, col, rowstart, cursor, dinv, b2, (float*)d_out, 0);
}

// Round 2
// 1189.346 us; speedup vs baseline: 1.2650x; 1.2650x over previous
//
#include <hip/hip_runtime.h>
#include <math.h>

#define NN   100000
#define HH   128
#define EXTD 768
#define EE   1600000
#define LNEPS 1e-5f

typedef __attribute__((ext_vector_type(8))) short bf16x8;
typedef __attribute__((ext_vector_type(4))) float f32x4;

// RNE hi-split: x = hi + lo, |lo| <= 2^-9 |x|; lo stored truncated (err <= 2^-17 |x|)
__device__ inline void bf16_split(float x, short& h, short& l) {
    unsigned int u  = __float_as_uint(x);
    unsigned int hb = (u + 0x7fffu + ((u >> 16) & 1u)) >> 16;
    h = (short)hb;
    float hf = __uint_as_float(hb << 16);
    l = (short)(__float_as_uint(x - hf) >> 16);
}

// ---------------- CSR build ----------------

__global__ void k_init(int* __restrict__ deg, int* __restrict__ counter) {
    int i = blockIdx.x * 256 + threadIdx.x;
    if (i < NN) deg[i] = 1;            // self loop contributes 1 to degree
    if (i == 0) *counter = 0;
}

__global__ void k_count(const int* __restrict__ dst, int* __restrict__ deg) {
    int e = blockIdx.x * 256 + threadIdx.x;
    if (e < EE) atomicAdd(&deg[dst[e]], 1);
}

__global__ void k_offsets(const int* __restrict__ deg, float* __restrict__ dinv,
                          int* __restrict__ rowstart, int* __restrict__ cursor,
                          int* __restrict__ counter) {
    int i = blockIdx.x * 256 + threadIdx.x;
    if (i < NN) {
        int d = deg[i];
        dinv[i] = rsqrtf((float)d);
        int rs = atomicAdd(counter, d - 1);   // in-degree excluding self loop
        rowstart[i] = rs;
        cursor[i]   = rs;
    }
}

__global__ void k_fill(const int* __restrict__ src, const int* __restrict__ dst,
                       int* __restrict__ cursor, int* __restrict__ col) {
    int e = blockIdx.x * 256 + threadIdx.x;
    if (e < EE) {
        int d = dst[e];
        int p = atomicAdd(&cursor[d], 1);
        col[p] = src[e];
    }
}

// ---------------- W pre-conversion to MFMA-fragment hi/lo layout ----------------
// Per 32-k block b: 8192 shorts: hi[cf 0..7][lane 0..63][j 0..7] then lo at +4096.
// Fragment element (cf, lane, j) = W[b*32 + (lane>>4)*8 + j][cf*16 + (lane&15)].

__global__ void k_wconv(const float* __restrict__ Wa, const float* __restrict__ Wb,
                        const float* __restrict__ Wc, const float* __restrict__ Wd,
                        const float* __restrict__ We,
                        short* __restrict__ Fa, short* __restrict__ Fb,
                        short* __restrict__ Fc, short* __restrict__ Fd,
                        short* __restrict__ Fe)
{
    int t = blockIdx.x * 256 + threadIdx.x;
    const float* W; short* F;
    if      (t < 12288) { W = Wa; F = Fa; }                    // K=768
    else if (t < 16384) { W = Wb; F = Fb; t -= 12288; }        // K=256
    else if (t < 18432) { W = Wc; F = Fc; t -= 16384; }        // K=128
    else if (t < 20480) { W = Wd; F = Fd; t -= 18432; }        // K=128
    else if (t < 22528) { W = We; F = Fe; t -= 20480; }        // K=128
    else return;
    const int b   = t >> 9;
    const int r   = t & 511;
    const int cf  = r >> 6;
    const int l   = r & 63;
    const int k0  = b * 32 + (l >> 4) * 8;
    const int col = cf * 16 + (l & 15);
    bf16x8 hv, lv;
#pragma unroll
    for (int j = 0; j < 8; ++j) {
        short h, lo;
        bf16_split(W[(size_t)(k0 + j) * 128 + col], h, lo);
        hv[j] = h; lv[j] = lo;
    }
    short* ph = F + (size_t)b * 8192 + (size_t)(cf * 64 + l) * 8;
    *(bf16x8*)ph            = hv;
    *(bf16x8*)(ph + 4096)   = lv;
}

// ---------------- GEMM via bf16x3-split MFMA ----------------
// C[N x 128] = A[N x K](f32) @ W[K x 128](pre-split frag layout) (+bias)(+LN+ReLU)(+rowscale)
// 128x128 tile, 256 threads = 4 waves; wave (wr,wc) owns 64x64 quadrant as 4x4
// mfma_f32_16x16x32_bf16 fragments. A is hi/lo-split on the fly during LDS staging,
// written in fragment order -> all ds_read_b128 lane-contiguous (conflict-free).

template<int LNRELU, int CONCAT, int ROWSCALE>
__global__ __launch_bounds__(256, 2)
void k_gemm(const float* __restrict__ A0, const float* __restrict__ A1,
            const short* __restrict__ Wf, const float* __restrict__ bias,
            const float* __restrict__ lng, const float* __restrict__ lnb,
            const float* __restrict__ rowscale,
            float* __restrict__ C, int K)
{
    __shared__ __align__(16) short Ash[8192];   // hi 0..4095 | lo 4096..8191
    __shared__ __align__(16) short Bsh[8192];
    __shared__ float lnS[2][128][2];            // LN cross-wave partials

    const int tid  = threadIdx.x;
    const int lane = tid & 63;
    const int wid  = tid >> 6;
    const int wr   = wid >> 1;        // row half (64 rows)
    const int wc   = wid & 1;         // col half (64 cols)
    const int row0 = blockIdx.x * 128;

    // A staging: thread covers row srow, 16 consecutive k starting at skh*16
    const int srow  = tid >> 1;           // 0..127
    const int skh   = tid & 1;            // 0/1
    const int garow = row0 + srow;

    f32x4 acc[4][4];
#pragma unroll
    for (int i = 0; i < 4; ++i)
#pragma unroll
        for (int j = 0; j < 4; ++j) acc[i][j] = (f32x4){0.f, 0.f, 0.f, 0.f};

    for (int k0 = 0; k0 < K; k0 += 32) {
        // ---- global loads (before barrier, overlap with previous compute) ----
        float a[16];
#pragma unroll
        for (int j = 0; j < 16; ++j) a[j] = 0.f;
        if (garow < NN) {
            const float* ap;
            if (CONCAT) {
                ap = (k0 < HH) ? (A0 + (size_t)garow * HH + k0)
                               : (A1 + (size_t)garow * HH + (k0 - HH));
            } else {
                ap = A0 + (size_t)garow * K + k0;
            }
            const float4 v0 = *(const float4*)(ap + skh * 16 + 0);
            const float4 v1 = *(const float4*)(ap + skh * 16 + 4);
            const float4 v2 = *(const float4*)(ap + skh * 16 + 8);
            const float4 v3 = *(const float4*)(ap + skh * 16 + 12);
            a[0]=v0.x; a[1]=v0.y; a[2]=v0.z;  a[3]=v0.w;
            a[4]=v1.x; a[5]=v1.y; a[6]=v1.z;  a[7]=v1.w;
            a[8]=v2.x; a[9]=v2.y; a[10]=v2.z; a[11]=v2.w;
            a[12]=v3.x; a[13]=v3.y; a[14]=v3.z; a[15]=v3.w;
        }
        const short* wp = Wf + (size_t)(k0 >> 5) * 8192 + tid * 32;
        bf16x8 wv[4];
#pragma unroll
        for (int j = 0; j < 4; ++j) wv[j] = *(const bf16x8*)(wp + j * 8);

        __syncthreads();   // previous iteration's fragment reads complete

        // ---- B: straight copy of pre-split fragments ----
        {
            short* bp = Bsh + tid * 32;
#pragma unroll
            for (int j = 0; j < 4; ++j) *(bf16x8*)(bp + j * 8) = wv[j];
        }
        // ---- A: split + write in fragment order ----
#pragma unroll
        for (int g = 0; g < 2; ++g) {
            bf16x8 hv, lv;
#pragma unroll
            for (int j = 0; j < 8; ++j) {
                short h, lo;
                bf16_split(a[g * 8 + j], h, lo);
                hv[j] = h; lv[j] = lo;
            }
            const int off = (((srow >> 4) * 64) + (((skh * 2 + g) << 4) | (srow & 15))) * 8;
            *(bf16x8*)(Ash + off)        = hv;
            *(bf16x8*)(Ash + 4096 + off) = lv;
        }
        __syncthreads();

        // ---- fragment reads (lane-contiguous b128) ----
        bf16x8 ah[4], al[4], bh[4], bl[4];
#pragma unroll
        for (int i = 0; i < 4; ++i) {
            const int ra = ((wr * 4 + i) * 64 + lane) * 8;
            ah[i] = *(const bf16x8*)(Ash + ra);
            al[i] = *(const bf16x8*)(Ash + 4096 + ra);
            const int rb = ((wc * 4 + i) * 64 + lane) * 8;
            bh[i] = *(const bf16x8*)(Bsh + rb);
            bl[i] = *(const bf16x8*)(Bsh + 4096 + rb);
        }
        // ---- 3-pass MFMA: hi*hi, hi*lo, lo*hi ----
#pragma unroll
        for (int i = 0; i < 4; ++i)
#pragma unroll
            for (int j = 0; j < 4; ++j)
                acc[i][j] = __builtin_amdgcn_mfma_f32_16x16x32_bf16(ah[i], bh[j], acc[i][j], 0, 0, 0);
#pragma unroll
        for (int i = 0; i < 4; ++i)
#pragma unroll
            for (int j = 0; j < 4; ++j)
                acc[i][j] = __builtin_amdgcn_mfma_f32_16x16x32_bf16(ah[i], bl[j], acc[i][j], 0, 0, 0);
#pragma unroll
        for (int i = 0; i < 4; ++i)
#pragma unroll
            for (int j = 0; j < 4; ++j)
                acc[i][j] = __builtin_amdgcn_mfma_f32_16x16x32_bf16(al[i], bh[j], acc[i][j], 0, 0, 0);
    }

    // ---- epilogue. C/D layout: col = lane&15, row = (lane>>4)*4 + reg ----
    const int colbase = wc * 64;
    const int c15     = lane & 15;
    const int r4      = (lane >> 4) * 4;

    if (bias != nullptr) {
        float qb[4];
#pragma unroll
        for (int c = 0; c < 4; ++c) qb[c] = bias[colbase + c * 16 + c15];
#pragma unroll
        for (int i = 0; i < 4; ++i)
#pragma unroll
            for (int c = 0; c < 4; ++c)
#pragma unroll
                for (int q = 0; q < 4; ++q) acc[i][c][q] += qb[c];
    }

    if constexpr (LNRELU) {
#pragma unroll
        for (int i = 0; i < 4; ++i)
#pragma unroll
            for (int q = 0; q < 4; ++q) {
                float s1 = 0.f, s2 = 0.f;
#pragma unroll
                for (int c = 0; c < 4; ++c) {
                    const float v = acc[i][c][q];
                    s1 += v; s2 = fmaf(v, v, s2);
                }
#pragma unroll
                for (int m = 1; m < 16; m <<= 1) {
                    s1 += __shfl_xor(s1, m);
                    s2 += __shfl_xor(s2, m);
                }
                if (c15 == 0) {
                    const int rl = wr * 64 + i * 16 + r4 + q;
                    lnS[wc][rl][0] = s1;
                    lnS[wc][rl][1] = s2;
                }
            }
        __syncthreads();
        float gg[4], hh[4];
#pragma unroll
        for (int c = 0; c < 4; ++c) {
            gg[c] = lng[colbase + c * 16 + c15];
            hh[c] = lnb[colbase + c * 16 + c15];
        }
#pragma unroll
        for (int i = 0; i < 4; ++i)
#pragma unroll
            for (int q = 0; q < 4; ++q) {
                const int rl = wr * 64 + i * 16 + r4 + q;
                const float s1 = lnS[0][rl][0] + lnS[1][rl][0];
                const float s2 = lnS[0][rl][1] + lnS[1][rl][1];
                const float mu  = s1 * (1.0f / HH);
                const float var = fmaf(-mu, mu, s2 * (1.0f / HH));
                const float rsd = rsqrtf(var + LNEPS);
#pragma unroll
                for (int c = 0; c < 4; ++c) {
                    float v = (acc[i][c][q] - mu) * rsd;
                    v = fmaf(v, gg[c], hh[c]);
                    acc[i][c][q] = fmaxf(v, 0.f);
                }
            }
    }

    if constexpr (ROWSCALE) {
#pragma unroll
        for (int i = 0; i < 4; ++i)
#pragma unroll
            for (int q = 0; q < 4; ++q) {
                const int rr = row0 + wr * 64 + i * 16 + r4 + q;
                const float sc = (rr < NN) ? rowscale[rr] : 0.f;
#pragma unroll
                for (int c = 0; c < 4; ++c) acc[i][c][q] *= sc;
            }
    }

#pragma unroll
    for (int i = 0; i < 4; ++i)
#pragma unroll
        for (int q = 0; q < 4; ++q) {
            const int rr = row0 + wr * 64 + i * 16 + r4 + q;
            if (rr < NN) {
                float* cp = C + (size_t)rr * 128 + colbase + c15;
#pragma unroll
                for (int c = 0; c < 4; ++c) cp[c * 16] = acc[i][c][q];
            }
        }
}

// ---------------- SpMM: out[d] = dinv[d]*(sum Z[src] + Z[d]) + bias, Z pre-scaled by dinv ----

__global__ __launch_bounds__(256)
void k_spmm(const float* __restrict__ Z, const int* __restrict__ col,
            const int* __restrict__ rs, const int* __restrict__ re,
            const float* __restrict__ dinv, const float* __restrict__ bias,
            float* __restrict__ out, int dorelu)
{
    int gid  = blockIdx.x * blockDim.x + threadIdx.x;
    int node = gid >> 6;
    int lane = threadIdx.x & 63;
    if (node >= NN) return;

    const int beg = rs[node];
    const int end = re[node];
    const float di = dinv[node];
    const size_t lofs = (size_t)(lane * 2);

    float ax, ay;
    {
        const float2 v = *(const float2*)(Z + (size_t)node * HH + lofs);
        ax = v.x;
        ay = v.y;
    }

    int e = beg;
    const int e8 = beg + ((end - beg) & ~7);
    for (; e < e8; e += 8) {
        int s[8];
#pragma unroll
        for (int q = 0; q < 8; ++q) s[q] = col[e + q];
        float2 v[8];
#pragma unroll
        for (int q = 0; q < 8; ++q)
            v[q] = *(const float2*)(Z + (size_t)s[q] * HH + lofs);
#pragma unroll
        for (int q = 0; q < 8; ++q) { ax += v[q].x; ay += v[q].y; }
    }
    for (; e < end; ++e) {
        const int s0 = col[e];
        const float2 v = *(const float2*)(Z + (size_t)s0 * HH + lofs);
        ax += v.x;
        ay += v.y;
    }

    float ox = fmaf(di, ax, bias[lane * 2]);
    float oy = fmaf(di, ay, bias[lane * 2 + 1]);
    if (dorelu) { ox = fmaxf(ox, 0.f); oy = fmaxf(oy, 0.f); }
    float2 o; o.x = ox; o.y = oy;
    *(float2*)(out + (size_t)node * HH + lofs) = o;
}

// ---------------- launch ----------------

extern "C" void kernel_launch(void* const* d_in, const int* in_sizes, int n_in,
                              void* d_out, int out_size, void* d_ws, size_t ws_size,
                              hipStream_t stream)
{
    const int*   ei    = (const int*)d_in[0];
    const float* ext   = (const float*)d_in[1];
    const float* emb   = (const float*)d_in[2];
    const float* encW  = (const float*)d_in[3];
    const float* encB  = (const float*)d_in[4];
    const float* lng   = (const float*)d_in[5];
    const float* lnb   = (const float*)d_in[6];
    const float* projW = (const float*)d_in[7];
    const float* projB = (const float*)d_in[8];
    const float* W0    = (const float*)d_in[9];
    const float* b0    = (const float*)d_in[10];
    const float* W1    = (const float*)d_in[11];
    const float* b1    = (const float*)d_in[12];
    const float* W2    = (const float*)d_in[13];
    const float* b2    = (const float*)d_in[14];

    const int* srcI = ei;        // edge_index[0]
    const int* dstI = ei + EE;   // edge_index[1]

    char* w = (char*)d_ws;
    size_t off = 0;
    auto alloc = [&](size_t bytes) -> void* {
        void* p = w + off;
        off += (bytes + 255) & ~(size_t)255;
        return p;
    };
    int*   deg      = (int*)alloc((size_t)NN * 4);
    float* dinv     = (float*)alloc((size_t)NN * 4);
    int*   rowstart = (int*)alloc((size_t)NN * 4);
    int*   cursor   = (int*)alloc((size_t)NN * 4);
    int*   counter  = (int*)alloc(256);
    int*   col      = (int*)alloc((size_t)EE * 4);
    float* bufA     = (float*)alloc((size_t)NN * HH * 4);
    float* bufB     = (float*)alloc((size_t)NN * HH * 4);
    // hi/lo fragment-layout weights: K*128*2 shorts = K*512 bytes
    short* wfE = (short*)alloc((size_t)768 * 512);
    short* wfP = (short*)alloc((size_t)256 * 512);
    short* wf0 = (short*)alloc((size_t)128 * 512);
    short* wf1 = (short*)alloc((size_t)128 * 512);
    short* wf2 = (short*)alloc((size_t)128 * 512);

    const int gN = (NN + 255) / 256;
    const int gE = (EE + 255) / 256;
    const int gG = (NN + 127) / 128;   // 128 rows per block
    const int gS = (NN + 3) / 4;       // 4 waves (nodes) per 256-thread block
    const int gW = (22528 + 255) / 256;

    k_wconv  <<<gW, 256, 0, stream>>>(encW, projW, W0, W1, W2, wfE, wfP, wf0, wf1, wf2);
    k_init   <<<gN, 256, 0, stream>>>(deg, counter);
    k_count  <<<gE, 256, 0, stream>>>(dstI, deg);
    k_offsets<<<gN, 256, 0, stream>>>(deg, dinv, rowstart, cursor, counter);
    k_fill   <<<gE, 256, 0, stream>>>(srcI, dstI, cursor, col);

    // feat = relu(LN(ext @ encW + encB))                    -> bufA
    k_gemm<1, 0, 0><<<gG, 256, 0, stream>>>(ext, nullptr, wfE, encB, lng, lnb, nullptr, bufA, EXTD);
    // x = concat(emb, feat) @ projW + projB                 -> bufB
    k_gemm<0, 1, 0><<<gG, 256, 0, stream>>>(emb, bufA, wfP, projB, nullptr, nullptr, nullptr, bufB, 2 * HH);
    // Z0 = dinv .* (x @ W0)                                 -> bufA
    k_gemm<0, 0, 1><<<gG, 256, 0, stream>>>(bufB, nullptr, wf0, nullptr, nullptr, nullptr, dinv, bufA, HH);
    // x = relu(dinv.*(sum Z0) + b0)                         -> bufB
    k_spmm<<<gS, 256, 0, stream>>>(bufA, col, rowstart, cursor, dinv, b0, bufB, 1);
    // Z1 = dinv .* (x @ W1)                                 -> bufA
    k_gemm<0, 0, 1><<<gG, 256, 0, stream>>>(bufB, nullptr, wf1, nullptr, nullptr, nullptr, dinv, bufA, HH);
    // x = relu(dinv.*(sum Z1) + b1)                         -> bufB
    k_spmm<<<gS, 256, 0, stream>>>(bufA, col, rowstart, cursor, dinv, b1, bufB, 1);
    // Z2 = dinv .* (x @ W2)                                 -> bufA
    k_gemm<0, 0, 1><<<gG, 256, 0, stream>>>(bufB, nullptr, wf2, nullptr, nullptr, nullptr, dinv, bufA, HH);
    // out = dinv.*(sum Z2) + b2                             -> d_out
    k_spmm<<<gS, 256, 0, stream>>>(bufA, col, rowstart, cursor, dinv, b2, (float*)d_out, 0);
}

// Round 3
// 1059.765 us; speedup vs baseline: 1.4197x; 1.1223x over previous
//
#include <hip/hip_runtime.h>
#include <math.h>

#define NN   100000
#define HH   128
#define EXTD 768
#define EE   1600000
#define LNEPS 1e-5f

typedef __attribute__((ext_vector_type(8))) short bf16x8;
typedef __attribute__((ext_vector_type(4))) float f32x4;

// RNE hi-split: x = hi + lo, |lo| <= 2^-9 |x|; lo stored truncated (err <= 2^-17 |x|)
__device__ inline void bf16_split(float x, short& h, short& l) {
    unsigned int u  = __float_as_uint(x);
    unsigned int hb = (u + 0x7fffu + ((u >> 16) & 1u)) >> 16;
    h = (short)hb;
    float hf = __uint_as_float(hb << 16);
    l = (short)(__float_as_uint(x - hf) >> 16);
}

__device__ inline unsigned short bf16_rne(float x) {
    unsigned int u = __float_as_uint(x);
    return (unsigned short)((u + 0x7fffu + ((u >> 16) & 1u)) >> 16);
}

// ---------------- CSR build ----------------

__global__ void k_init(int* __restrict__ deg, int* __restrict__ counter) {
    int i = blockIdx.x * 256 + threadIdx.x;
    if (i < NN) deg[i] = 1;            // self loop contributes 1 to degree
    if (i == 0) *counter = 0;
}

__global__ void k_count(const int* __restrict__ dst, int* __restrict__ deg) {
    int e = blockIdx.x * 256 + threadIdx.x;
    if (e < EE) atomicAdd(&deg[dst[e]], 1);
}

__global__ void k_offsets(const int* __restrict__ deg, float* __restrict__ dinv,
                          int* __restrict__ rowstart, int* __restrict__ cursor,
                          int* __restrict__ counter) {
    int i = blockIdx.x * 256 + threadIdx.x;
    if (i < NN) {
        int d = deg[i];
        dinv[i] = rsqrtf((float)d);
        int rs = atomicAdd(counter, d - 1);   // in-degree excluding self loop
        rowstart[i] = rs;
        cursor[i]   = rs;
    }
}

__global__ void k_fill(const int* __restrict__ src, const int* __restrict__ dst,
                       int* __restrict__ cursor, int* __restrict__ col) {
    int e = blockIdx.x * 256 + threadIdx.x;
    if (e < EE) {
        int d = dst[e];
        int p = atomicAdd(&cursor[d], 1);
        col[p] = src[e];
    }
}

// ---------------- W pre-conversion to MFMA-fragment hi/lo layout ----------------
// Per 32-k block b: 8192 shorts: hi[cf 0..7][lane 0..63][j 0..7] then lo at +4096.
// Fragment element (cf, lane, j) = W[b*32 + (lane>>4)*8 + j][cf*16 + (lane&15)].

__global__ void k_wconv(const float* __restrict__ Wa, const float* __restrict__ Wb,
                        const float* __restrict__ Wc, const float* __restrict__ Wd,
                        const float* __restrict__ We,
                        short* __restrict__ Fa, short* __restrict__ Fb,
                        short* __restrict__ Fc, short* __restrict__ Fd,
                        short* __restrict__ Fe)
{
    int t = blockIdx.x * 256 + threadIdx.x;
    const float* W; short* F;
    if      (t < 12288) { W = Wa; F = Fa; }                    // K=768
    else if (t < 16384) { W = Wb; F = Fb; t -= 12288; }        // K=256
    else if (t < 18432) { W = Wc; F = Fc; t -= 16384; }        // K=128
    else if (t < 20480) { W = Wd; F = Fd; t -= 18432; }        // K=128
    else if (t < 22528) { W = We; F = Fe; t -= 20480; }        // K=128
    else return;
    const int b   = t >> 9;
    const int r   = t & 511;
    const int cf  = r >> 6;
    const int l   = r & 63;
    const int k0  = b * 32 + (l >> 4) * 8;
    const int col = cf * 16 + (l & 15);
    bf16x8 hv, lv;
#pragma unroll
    for (int j = 0; j < 8; ++j) {
        short h, lo;
        bf16_split(W[(size_t)(k0 + j) * 128 + col], h, lo);
        hv[j] = h; lv[j] = lo;
    }
    short* ph = F + (size_t)b * 8192 + (size_t)(cf * 64 + l) * 8;
    *(bf16x8*)ph            = hv;
    *(bf16x8*)(ph + 4096)   = lv;
}

// ---------------- GEMM via bf16x3-split MFMA ----------------
// C[N x 128] = A[N x K](f32) @ W[K x 128](pre-split frag layout) (+bias)(+LN+ReLU)
// ZOUT: apply rowscale and store bf16 (Z buffer for SpMM); else store f32.
// 128x128 tile, 256 threads = 4 waves; wave (wr,wc) owns 64x64 quadrant as 4x4
// mfma_f32_16x16x32_bf16 fragments.

template<int LNRELU, int CONCAT, int ZOUT>
__global__ __launch_bounds__(256, 2)
void k_gemm(const float* __restrict__ A0, const float* __restrict__ A1,
            const short* __restrict__ Wf, const float* __restrict__ bias,
            const float* __restrict__ lng, const float* __restrict__ lnb,
            const float* __restrict__ rowscale,
            void* __restrict__ Cout, int K)
{
    __shared__ __align__(16) short Ash[8192];   // hi 0..4095 | lo 4096..8191
    __shared__ __align__(16) short Bsh[8192];
    __shared__ float lnS[2][128][2];            // LN cross-wave partials

    const int tid  = threadIdx.x;
    const int lane = tid & 63;
    const int wid  = tid >> 6;
    const int wr   = wid >> 1;        // row half (64 rows)
    const int wc   = wid & 1;         // col half (64 cols)
    const int row0 = blockIdx.x * 128;

    // A staging: thread covers row srow, 16 consecutive k starting at skh*16
    const int srow  = tid >> 1;           // 0..127
    const int skh   = tid & 1;            // 0/1
    const int garow = row0 + srow;

    f32x4 acc[4][4];
#pragma unroll
    for (int i = 0; i < 4; ++i)
#pragma unroll
        for (int j = 0; j < 4; ++j) acc[i][j] = (f32x4){0.f, 0.f, 0.f, 0.f};

    for (int k0 = 0; k0 < K; k0 += 32) {
        // ---- global loads (before barrier, overlap with previous compute) ----
        float a[16];
#pragma unroll
        for (int j = 0; j < 16; ++j) a[j] = 0.f;
        if (garow < NN) {
            const float* ap;
            if (CONCAT) {
                ap = (k0 < HH) ? (A0 + (size_t)garow * HH + k0)
                               : (A1 + (size_t)garow * HH + (k0 - HH));
            } else {
                ap = A0 + (size_t)garow * K + k0;
            }
            const float4 v0 = *(const float4*)(ap + skh * 16 + 0);
            const float4 v1 = *(const float4*)(ap + skh * 16 + 4);
            const float4 v2 = *(const float4*)(ap + skh * 16 + 8);
            const float4 v3 = *(const float4*)(ap + skh * 16 + 12);
            a[0]=v0.x; a[1]=v0.y; a[2]=v0.z;  a[3]=v0.w;
            a[4]=v1.x; a[5]=v1.y; a[6]=v1.z;  a[7]=v1.w;
            a[8]=v2.x; a[9]=v2.y; a[10]=v2.z; a[11]=v2.w;
            a[12]=v3.x; a[13]=v3.y; a[14]=v3.z; a[15]=v3.w;
        }
        const short* wp = Wf + (size_t)(k0 >> 5) * 8192 + tid * 32;
        bf16x8 wv[4];
#pragma unroll
        for (int j = 0; j < 4; ++j) wv[j] = *(const bf16x8*)(wp + j * 8);

        __syncthreads();   // previous iteration's fragment reads complete

        // ---- B: straight copy of pre-split fragments ----
        {
            short* bp = Bsh + tid * 32;
#pragma unroll
            for (int j = 0; j < 4; ++j) *(bf16x8*)(bp + j * 8) = wv[j];
        }
        // ---- A: split + write in fragment order ----
#pragma unroll
        for (int g = 0; g < 2; ++g) {
            bf16x8 hv, lv;
#pragma unroll
            for (int j = 0; j < 8; ++j) {
                short h, lo;
                bf16_split(a[g * 8 + j], h, lo);
                hv[j] = h; lv[j] = lo;
            }
            const int off = (((srow >> 4) * 64) + (((skh * 2 + g) << 4) | (srow & 15))) * 8;
            *(bf16x8*)(Ash + off)        = hv;
            *(bf16x8*)(Ash + 4096 + off) = lv;
        }
        __syncthreads();

        // ---- fragment reads (lane-contiguous b128) ----
        bf16x8 ah[4], al[4], bh[4], bl[4];
#pragma unroll
        for (int i = 0; i < 4; ++i) {
            const int ra = ((wr * 4 + i) * 64 + lane) * 8;
            ah[i] = *(const bf16x8*)(Ash + ra);
            al[i] = *(const bf16x8*)(Ash + 4096 + ra);
            const int rb = ((wc * 4 + i) * 64 + lane) * 8;
            bh[i] = *(const bf16x8*)(Bsh + rb);
            bl[i] = *(const bf16x8*)(Bsh + 4096 + rb);
        }
        // ---- 3-pass MFMA: hi*hi, hi*lo, lo*hi ----
#pragma unroll
        for (int i = 0; i < 4; ++i)
#pragma unroll
            for (int j = 0; j < 4; ++j)
                acc[i][j] = __builtin_amdgcn_mfma_f32_16x16x32_bf16(ah[i], bh[j], acc[i][j], 0, 0, 0);
#pragma unroll
        for (int i = 0; i < 4; ++i)
#pragma unroll
            for (int j = 0; j < 4; ++j)
                acc[i][j] = __builtin_amdgcn_mfma_f32_16x16x32_bf16(ah[i], bl[j], acc[i][j], 0, 0, 0);
#pragma unroll
        for (int i = 0; i < 4; ++i)
#pragma unroll
            for (int j = 0; j < 4; ++j)
                acc[i][j] = __builtin_amdgcn_mfma_f32_16x16x32_bf16(al[i], bh[j], acc[i][j], 0, 0, 0);
    }

    // ---- epilogue. C/D layout: col = lane&15, row = (lane>>4)*4 + reg ----
    const int colbase = wc * 64;
    const int c15     = lane & 15;
    const int r4      = (lane >> 4) * 4;

    if (bias != nullptr) {
        float qb[4];
#pragma unroll
        for (int c = 0; c < 4; ++c) qb[c] = bias[colbase + c * 16 + c15];
#pragma unroll
        for (int i = 0; i < 4; ++i)
#pragma unroll
            for (int c = 0; c < 4; ++c)
#pragma unroll
                for (int q = 0; q < 4; ++q) acc[i][c][q] += qb[c];
    }

    if constexpr (LNRELU) {
#pragma unroll
        for (int i = 0; i < 4; ++i)
#pragma unroll
            for (int q = 0; q < 4; ++q) {
                float s1 = 0.f, s2 = 0.f;
#pragma unroll
                for (int c = 0; c < 4; ++c) {
                    const float v = acc[i][c][q];
                    s1 += v; s2 = fmaf(v, v, s2);
                }
#pragma unroll
                for (int m = 1; m < 16; m <<= 1) {
                    s1 += __shfl_xor(s1, m);
                    s2 += __shfl_xor(s2, m);
                }
                if (c15 == 0) {
                    const int rl = wr * 64 + i * 16 + r4 + q;
                    lnS[wc][rl][0] = s1;
                    lnS[wc][rl][1] = s2;
                }
            }
        __syncthreads();
        float gg[4], hh[4];
#pragma unroll
        for (int c = 0; c < 4; ++c) {
            gg[c] = lng[colbase + c * 16 + c15];
            hh[c] = lnb[colbase + c * 16 + c15];
        }
#pragma unroll
        for (int i = 0; i < 4; ++i)
#pragma unroll
            for (int q = 0; q < 4; ++q) {
                const int rl = wr * 64 + i * 16 + r4 + q;
                const float s1 = lnS[0][rl][0] + lnS[1][rl][0];
                const float s2 = lnS[0][rl][1] + lnS[1][rl][1];
                const float mu  = s1 * (1.0f / HH);
                const float var = fmaf(-mu, mu, s2 * (1.0f / HH));
                const float rsd = rsqrtf(var + LNEPS);
#pragma unroll
                for (int c = 0; c < 4; ++c) {
                    float v = (acc[i][c][q] - mu) * rsd;
                    v = fmaf(v, gg[c], hh[c]);
                    acc[i][c][q] = fmaxf(v, 0.f);
                }
            }
    }

    if constexpr (ZOUT) {
        // rowscale + pack bf16, store to ushort Z buffer
        unsigned short* Cb = (unsigned short*)Cout;
#pragma unroll
        for (int i = 0; i < 4; ++i)
#pragma unroll
            for (int q = 0; q < 4; ++q) {
                const int rr = row0 + wr * 64 + i * 16 + r4 + q;
                if (rr < NN) {
                    const float sc = rowscale[rr];
                    unsigned short* cp = Cb + (size_t)rr * 128 + colbase + c15;
#pragma unroll
                    for (int c = 0; c < 4; ++c) cp[c * 16] = bf16_rne(acc[i][c][q] * sc);
                }
            }
    } else {
        float* C = (float*)Cout;
#pragma unroll
        for (int i = 0; i < 4; ++i)
#pragma unroll
            for (int q = 0; q < 4; ++q) {
                const int rr = row0 + wr * 64 + i * 16 + r4 + q;
                if (rr < NN) {
                    float* cp = C + (size_t)rr * 128 + colbase + c15;
#pragma unroll
                    for (int c = 0; c < 4; ++c) cp[c * 16] = acc[i][c][q];
                }
            }
    }
}

// ---------------- SpMM: out[d] = dinv[d]*(sum Z[src] + Z[d]) + bias ----
// Z is bf16 [NN][128], pre-scaled by dinv[src]. Wave per node; lane owns
// channels (2l, 2l+1) = one u32. fp32 accumulate. 256 B contiguous per row gather.

__global__ __launch_bounds__(256)
void k_spmm(const unsigned short* __restrict__ Z, const int* __restrict__ col,
            const int* __restrict__ rs, const int* __restrict__ re,
            const float* __restrict__ dinv, const float* __restrict__ bias,
            float* __restrict__ out, int dorelu)
{
    int gid  = blockIdx.x * blockDim.x + threadIdx.x;
    int node = gid >> 6;
    int lane = threadIdx.x & 63;
    if (node >= NN) return;

    const int beg = rs[node];
    const int end = re[node];
    const float di = dinv[node];

    float ax, ay;
    {   // self loop: Z[d] already = dinv[d]*Y[d]
        const unsigned int u = *(const unsigned int*)(Z + (size_t)node * HH + lane * 2);
        ax = __uint_as_float(u << 16);
        ay = __uint_as_float(u & 0xffff0000u);
    }

    int e = beg;
    const int e8 = beg + ((end - beg) & ~7);
    for (; e < e8; e += 8) {
        int s[8];
#pragma unroll
        for (int q = 0; q < 8; ++q) s[q] = col[e + q];
        unsigned int v[8];
#pragma unroll
        for (int q = 0; q < 8; ++q)
            v[q] = *(const unsigned int*)(Z + (size_t)s[q] * HH + lane * 2);
#pragma unroll
        for (int q = 0; q < 8; ++q) {
            ax += __uint_as_float(v[q] << 16);
            ay += __uint_as_float(v[q] & 0xffff0000u);
        }
    }
    for (; e < end; ++e) {
        const unsigned int u = *(const unsigned int*)(Z + (size_t)col[e] * HH + lane * 2);
        ax += __uint_as_float(u << 16);
        ay += __uint_as_float(u & 0xffff0000u);
    }

    float ox = fmaf(di, ax, bias[lane * 2]);
    float oy = fmaf(di, ay, bias[lane * 2 + 1]);
    if (dorelu) { ox = fmaxf(ox, 0.f); oy = fmaxf(oy, 0.f); }
    float2 o; o.x = ox; o.y = oy;
    *(float2*)(out + (size_t)node * HH + lane * 2) = o;
}

// ---------------- launch ----------------

extern "C" void kernel_launch(void* const* d_in, const int* in_sizes, int n_in,
                              void* d_out, int out_size, void* d_ws, size_t ws_size,
                              hipStream_t stream)
{
    const int*   ei    = (const int*)d_in[0];
    const float* ext   = (const float*)d_in[1];
    const float* emb   = (const float*)d_in[2];
    const float* encW  = (const float*)d_in[3];
    const float* encB  = (const float*)d_in[4];
    const float* lng   = (const float*)d_in[5];
    const float* lnb   = (const float*)d_in[6];
    const float* projW = (const float*)d_in[7];
    const float* projB = (const float*)d_in[8];
    const float* W0    = (const float*)d_in[9];
    const float* b0    = (const float*)d_in[10];
    const float* W1    = (const float*)d_in[11];
    const float* b1    = (const float*)d_in[12];
    const float* W2    = (const float*)d_in[13];
    const float* b2    = (const float*)d_in[14];

    const int* srcI = ei;        // edge_index[0]
    const int* dstI = ei + EE;   // edge_index[1]

    char* w = (char*)d_ws;
    size_t off = 0;
    auto alloc = [&](size_t bytes) -> void* {
        void* p = w + off;
        off += (bytes + 255) & ~(size_t)255;
        return p;
    };
    int*   deg      = (int*)alloc((size_t)NN * 4);
    float* dinv     = (float*)alloc((size_t)NN * 4);
    int*   rowstart = (int*)alloc((size_t)NN * 4);
    int*   cursor   = (int*)alloc((size_t)NN * 4);
    int*   counter  = (int*)alloc(256);
    int*   col      = (int*)alloc((size_t)EE * 4);
    float* bufX     = (float*)alloc((size_t)NN * HH * 4);   // fp32 x / feat
    float* bufF     = (float*)alloc((size_t)NN * HH * 4);   // fp32 feat (GEMM1 out)
    unsigned short* bufZ = (unsigned short*)alloc((size_t)NN * HH * 2);  // bf16 Z
    // hi/lo fragment-layout weights: K*128*2 shorts = K*512 bytes
    short* wfE = (short*)alloc((size_t)768 * 512);
    short* wfP = (short*)alloc((size_t)256 * 512);
    short* wf0 = (short*)alloc((size_t)128 * 512);
    short* wf1 = (short*)alloc((size_t)128 * 512);
    short* wf2 = (short*)alloc((size_t)128 * 512);

    const int gN = (NN + 255) / 256;
    const int gE = (EE + 255) / 256;
    const int gG = (NN + 127) / 128;   // 128 rows per block
    const int gS = (NN + 3) / 4;       // 4 waves (nodes) per 256-thread block
    const int gW = (22528 + 255) / 256;

    k_wconv  <<<gW, 256, 0, stream>>>(encW, projW, W0, W1, W2, wfE, wfP, wf0, wf1, wf2);
    k_init   <<<gN, 256, 0, stream>>>(deg, counter);
    k_count  <<<gE, 256, 0, stream>>>(dstI, deg);
    k_offsets<<<gN, 256, 0, stream>>>(deg, dinv, rowstart, cursor, counter);
    k_fill   <<<gE, 256, 0, stream>>>(srcI, dstI, cursor, col);

    // feat = relu(LN(ext @ encW + encB))                    -> bufF (f32)
    k_gemm<1, 0, 0><<<gG, 256, 0, stream>>>(ext, nullptr, wfE, encB, lng, lnb, nullptr, bufF, EXTD);
    // x = concat(emb, feat) @ projW + projB                 -> bufX (f32)
    k_gemm<0, 1, 0><<<gG, 256, 0, stream>>>(emb, bufF, wfP, projB, nullptr, nullptr, nullptr, bufX, 2 * HH);
    // Z0 = bf16(dinv .* (x @ W0))                           -> bufZ
    k_gemm<0, 0, 1><<<gG, 256, 0, stream>>>(bufX, nullptr, wf0, nullptr, nullptr, nullptr, dinv, bufZ, HH);
    // x = relu(dinv.*(sum Z0) + b0)                         -> bufX
    k_spmm<<<gS, 256, 0, stream>>>(bufZ, col, rowstart, cursor, dinv, b0, bufX, 1);
    // Z1 = bf16(dinv .* (x @ W1))                           -> bufZ
    k_gemm<0, 0, 1><<<gG, 256, 0, stream>>>(bufX, nullptr, wf1, nullptr, nullptr, nullptr, dinv, bufZ, HH);
    // x = relu(dinv.*(sum Z1) + b1)                         -> bufX
    k_spmm<<<gS, 256, 0, stream>>>(bufZ, col, rowstart, cursor, dinv, b1, bufX, 1);
    // Z2 = bf16(dinv .* (x @ W2))                           -> bufZ
    k_gemm<0, 0, 1><<<gG, 256, 0, stream>>>(bufX, nullptr, wf2, nullptr, nullptr, nullptr, dinv, bufZ, HH);
    // out = dinv.*(sum Z2) + b2                             -> d_out
    k_spmm<<<gS, 256, 0, stream>>>(bufZ, col, rowstart, cursor, dinv, b2, (float*)d_out, 0);
}

// Round 4
// 980.591 us; speedup vs baseline: 1.5343x; 1.0807x over previous
//
#include <hip/hip_runtime.h>
#include <math.h>

#define NN   100000
#define HH   128
#define EXTD 768
#define EE   1600000
#define LNEPS 1e-5f

typedef __attribute__((ext_vector_type(8))) short bf16x8;
typedef __attribute__((ext_vector_type(4))) float f32x4;

// RNE hi-split: x = hi + lo, |lo| <= 2^-9 |x|; lo stored truncated (err <= 2^-17 |x|)
__device__ inline void bf16_split(float x, short& h, short& l) {
    unsigned int u  = __float_as_uint(x);
    unsigned int hb = (u + 0x7fffu + ((u >> 16) & 1u)) >> 16;
    h = (short)hb;
    float hf = __uint_as_float(hb << 16);
    l = (short)(__float_as_uint(x - hf) >> 16);
}

__device__ inline unsigned short bf16_rne(float x) {
    unsigned int u = __float_as_uint(x);
    return (unsigned short)((u + 0x7fffu + ((u >> 16) & 1u)) >> 16);
}

// ---------------- CSR build ----------------
// count: lidx[e] = old deg value (>=1, self loop pre-counted) -> fill needs no atomic.
// offsets: wave-scan + 1 atomic per wave (vs 100K to one address).

__global__ void k_init(int* __restrict__ deg, int* __restrict__ counter) {
    int i = blockIdx.x * 256 + threadIdx.x;
    if (i < NN) deg[i] = 1;            // self loop contributes 1 to degree
    if (i == 0) *counter = 0;
}

__global__ void k_count(const int* __restrict__ dst, int* __restrict__ deg,
                        int* __restrict__ lidx) {
    int e = blockIdx.x * 256 + threadIdx.x;
    if (e < EE) lidx[e] = atomicAdd(&deg[dst[e]], 1);
}

__global__ void k_offsets(const int* __restrict__ deg, float* __restrict__ dinv,
                          int* __restrict__ rowstart, int* __restrict__ counter) {
    int i = blockIdx.x * 256 + threadIdx.x;
    const int lane = threadIdx.x & 63;
    int v = 0;
    if (i < NN) {
        int d = deg[i];
        dinv[i] = rsqrtf((float)d);
        v = d - 1;                       // in-degree excluding self loop
    }
    // wave inclusive scan of v
    int scan = v;
#pragma unroll
    for (int m = 1; m < 64; m <<= 1) {
        int t = __shfl_up(scan, m);
        if (lane >= m) scan += t;
    }
    const int total = __shfl(scan, 63);
    int base = 0;
    if (lane == 63) base = atomicAdd(counter, total);
    base = __shfl(base, 63);
    if (i < NN) rowstart[i] = base + scan - v;   // exclusive scan + wave base
}

__global__ void k_fill(const int* __restrict__ src, const int* __restrict__ dst,
                       const int* __restrict__ lidx, const int* __restrict__ rowstart,
                       int* __restrict__ col) {
    int e = blockIdx.x * 256 + threadIdx.x;
    if (e < EE) {
        const int d = dst[e];
        col[rowstart[d] + lidx[e] - 1] = src[e];   // rowstart[] is L2-resident (400 KB)
    }
}

// ---------------- W pre-conversion to MFMA-fragment hi/lo layout ----------------
// Per 32-k block b: 8192 shorts: hi[cf 0..7][lane 0..63][j 0..7] then lo at +4096.
// Fragment element (cf, lane, j) = W[b*32 + (lane>>4)*8 + j][cf*16 + (lane&15)].

__global__ void k_wconv(const float* __restrict__ Wa, const float* __restrict__ Wb,
                        const float* __restrict__ Wc, const float* __restrict__ Wd,
                        const float* __restrict__ We,
                        short* __restrict__ Fa, short* __restrict__ Fb,
                        short* __restrict__ Fc, short* __restrict__ Fd,
                        short* __restrict__ Fe)
{
    int t = blockIdx.x * 256 + threadIdx.x;
    const float* W; short* F;
    if      (t < 12288) { W = Wa; F = Fa; }                    // K=768
    else if (t < 16384) { W = Wb; F = Fb; t -= 12288; }        // K=256
    else if (t < 18432) { W = Wc; F = Fc; t -= 16384; }        // K=128
    else if (t < 20480) { W = Wd; F = Fd; t -= 18432; }        // K=128
    else if (t < 22528) { W = We; F = Fe; t -= 20480; }        // K=128
    else return;
    const int b   = t >> 9;
    const int r   = t & 511;
    const int cf  = r >> 6;
    const int l   = r & 63;
    const int k0  = b * 32 + (l >> 4) * 8;
    const int col = cf * 16 + (l & 15);
    bf16x8 hv, lv;
#pragma unroll
    for (int j = 0; j < 8; ++j) {
        short h, lo;
        bf16_split(W[(size_t)(k0 + j) * 128 + col], h, lo);
        hv[j] = h; lv[j] = lo;
    }
    short* ph = F + (size_t)b * 8192 + (size_t)(cf * 64 + l) * 8;
    *(bf16x8*)ph            = hv;
    *(bf16x8*)(ph + 4096)   = lv;
}

// ---------------- GEMM via bf16x3-split MFMA ----------------
// C[N x 128] = A[N x K](f32) @ W[K x 128](pre-split frag layout) (+bias)(+LN+ReLU)
// ZOUT: apply rowscale and store bf16 (Z buffer for SpMM); else store f32.
// 128x128 tile, 256 threads = 4 waves; wave (wr,wc) owns 64x64 quadrant as 4x4
// mfma_f32_16x16x32_bf16 fragments.

template<int LNRELU, int CONCAT, int ZOUT>
__global__ __launch_bounds__(256, 2)
void k_gemm(const float* __restrict__ A0, const float* __restrict__ A1,
            const short* __restrict__ Wf, const float* __restrict__ bias,
            const float* __restrict__ lng, const float* __restrict__ lnb,
            const float* __restrict__ rowscale,
            void* __restrict__ Cout, int K)
{
    __shared__ __align__(16) short Ash[8192];   // hi 0..4095 | lo 4096..8191
    __shared__ __align__(16) short Bsh[8192];
    __shared__ float lnS[2][128][2];            // LN cross-wave partials

    const int tid  = threadIdx.x;
    const int lane = tid & 63;
    const int wid  = tid >> 6;
    const int wr   = wid >> 1;        // row half (64 rows)
    const int wc   = wid & 1;         // col half (64 cols)
    const int row0 = blockIdx.x * 128;

    // A staging: thread covers row srow, 16 consecutive k starting at skh*16
    const int srow  = tid >> 1;           // 0..127
    const int skh   = tid & 1;            // 0/1
    const int garow = row0 + srow;

    f32x4 acc[4][4];
#pragma unroll
    for (int i = 0; i < 4; ++i)
#pragma unroll
        for (int j = 0; j < 4; ++j) acc[i][j] = (f32x4){0.f, 0.f, 0.f, 0.f};

    for (int k0 = 0; k0 < K; k0 += 32) {
        // ---- global loads (before barrier, overlap with previous compute) ----
        float a[16];
#pragma unroll
        for (int j = 0; j < 16; ++j) a[j] = 0.f;
        if (garow < NN) {
            const float* ap;
            if (CONCAT) {
                ap = (k0 < HH) ? (A0 + (size_t)garow * HH + k0)
                               : (A1 + (size_t)garow * HH + (k0 - HH));
            } else {
                ap = A0 + (size_t)garow * K + k0;
            }
            const float4 v0 = *(const float4*)(ap + skh * 16 + 0);
            const float4 v1 = *(const float4*)(ap + skh * 16 + 4);
            const float4 v2 = *(const float4*)(ap + skh * 16 + 8);
            const float4 v3 = *(const float4*)(ap + skh * 16 + 12);
            a[0]=v0.x; a[1]=v0.y; a[2]=v0.z;  a[3]=v0.w;
            a[4]=v1.x; a[5]=v1.y; a[6]=v1.z;  a[7]=v1.w;
            a[8]=v2.x; a[9]=v2.y; a[10]=v2.z; a[11]=v2.w;
            a[12]=v3.x; a[13]=v3.y; a[14]=v3.z; a[15]=v3.w;
        }
        const short* wp = Wf + (size_t)(k0 >> 5) * 8192 + tid * 32;
        bf16x8 wv[4];
#pragma unroll
        for (int j = 0; j < 4; ++j) wv[j] = *(const bf16x8*)(wp + j * 8);

        __syncthreads();   // previous iteration's fragment reads complete

        // ---- B: straight copy of pre-split fragments ----
        {
            short* bp = Bsh + tid * 32;
#pragma unroll
            for (int j = 0; j < 4; ++j) *(bf16x8*)(bp + j * 8) = wv[j];
        }
        // ---- A: split + write in fragment order ----
#pragma unroll
        for (int g = 0; g < 2; ++g) {
            bf16x8 hv, lv;
#pragma unroll
            for (int j = 0; j < 8; ++j) {
                short h, lo;
                bf16_split(a[g * 8 + j], h, lo);
                hv[j] = h; lv[j] = lo;
            }
            const int off = (((srow >> 4) * 64) + (((skh * 2 + g) << 4) | (srow & 15))) * 8;
            *(bf16x8*)(Ash + off)        = hv;
            *(bf16x8*)(Ash + 4096 + off) = lv;
        }
        __syncthreads();

        // ---- fragment reads (lane-contiguous b128) ----
        bf16x8 ah[4], al[4], bh[4], bl[4];
#pragma unroll
        for (int i = 0; i < 4; ++i) {
            const int ra = ((wr * 4 + i) * 64 + lane) * 8;
            ah[i] = *(const bf16x8*)(Ash + ra);
            al[i] = *(const bf16x8*)(Ash + 4096 + ra);
            const int rb = ((wc * 4 + i) * 64 + lane) * 8;
            bh[i] = *(const bf16x8*)(Bsh + rb);
            bl[i] = *(const bf16x8*)(Bsh + 4096 + rb);
        }
        // ---- 3-pass MFMA: hi*hi, hi*lo, lo*hi ----
#pragma unroll
        for (int i = 0; i < 4; ++i)
#pragma unroll
            for (int j = 0; j < 4; ++j)
                acc[i][j] = __builtin_amdgcn_mfma_f32_16x16x32_bf16(ah[i], bh[j], acc[i][j], 0, 0, 0);
#pragma unroll
        for (int i = 0; i < 4; ++i)
#pragma unroll
            for (int j = 0; j < 4; ++j)
                acc[i][j] = __builtin_amdgcn_mfma_f32_16x16x32_bf16(ah[i], bl[j], acc[i][j], 0, 0, 0);
#pragma unroll
        for (int i = 0; i < 4; ++i)
#pragma unroll
            for (int j = 0; j < 4; ++j)
                acc[i][j] = __builtin_amdgcn_mfma_f32_16x16x32_bf16(al[i], bh[j], acc[i][j], 0, 0, 0);
    }

    // ---- epilogue. C/D layout: col = lane&15, row = (lane>>4)*4 + reg ----
    const int colbase = wc * 64;
    const int c15     = lane & 15;
    const int r4      = (lane >> 4) * 4;

    if (bias != nullptr) {
        float qb[4];
#pragma unroll
        for (int c = 0; c < 4; ++c) qb[c] = bias[colbase + c * 16 + c15];
#pragma unroll
        for (int i = 0; i < 4; ++i)
#pragma unroll
            for (int c = 0; c < 4; ++c)
#pragma unroll
                for (int q = 0; q < 4; ++q) acc[i][c][q] += qb[c];
    }

    if constexpr (LNRELU) {
#pragma unroll
        for (int i = 0; i < 4; ++i)
#pragma unroll
            for (int q = 0; q < 4; ++q) {
                float s1 = 0.f, s2 = 0.f;
#pragma unroll
                for (int c = 0; c < 4; ++c) {
                    const float v = acc[i][c][q];
                    s1 += v; s2 = fmaf(v, v, s2);
                }
#pragma unroll
                for (int m = 1; m < 16; m <<= 1) {
                    s1 += __shfl_xor(s1, m);
                    s2 += __shfl_xor(s2, m);
                }
                if (c15 == 0) {
                    const int rl = wr * 64 + i * 16 + r4 + q;
                    lnS[wc][rl][0] = s1;
                    lnS[wc][rl][1] = s2;
                }
            }
        __syncthreads();
        float gg[4], hh[4];
#pragma unroll
        for (int c = 0; c < 4; ++c) {
            gg[c] = lng[colbase + c * 16 + c15];
            hh[c] = lnb[colbase + c * 16 + c15];
        }
#pragma unroll
        for (int i = 0; i < 4; ++i)
#pragma unroll
            for (int q = 0; q < 4; ++q) {
                const int rl = wr * 64 + i * 16 + r4 + q;
                const float s1 = lnS[0][rl][0] + lnS[1][rl][0];
                const float s2 = lnS[0][rl][1] + lnS[1][rl][1];
                const float mu  = s1 * (1.0f / HH);
                const float var = fmaf(-mu, mu, s2 * (1.0f / HH));
                const float rsd = rsqrtf(var + LNEPS);
#pragma unroll
                for (int c = 0; c < 4; ++c) {
                    float v = (acc[i][c][q] - mu) * rsd;
                    v = fmaf(v, gg[c], hh[c]);
                    acc[i][c][q] = fmaxf(v, 0.f);
                }
            }
    }

    if constexpr (ZOUT) {
        // rowscale + pack bf16, store to ushort Z buffer
        unsigned short* Cb = (unsigned short*)Cout;
#pragma unroll
        for (int i = 0; i < 4; ++i)
#pragma unroll
            for (int q = 0; q < 4; ++q) {
                const int rr = row0 + wr * 64 + i * 16 + r4 + q;
                if (rr < NN) {
                    const float sc = rowscale[rr];
                    unsigned short* cp = Cb + (size_t)rr * 128 + colbase + c15;
#pragma unroll
                    for (int c = 0; c < 4; ++c) cp[c * 16] = bf16_rne(acc[i][c][q] * sc);
                }
            }
    } else {
        float* C = (float*)Cout;
#pragma unroll
        for (int i = 0; i < 4; ++i)
#pragma unroll
            for (int q = 0; q < 4; ++q) {
                const int rr = row0 + wr * 64 + i * 16 + r4 + q;
                if (rr < NN) {
                    float* cp = C + (size_t)rr * 128 + colbase + c15;
#pragma unroll
                    for (int c = 0; c < 4; ++c) cp[c * 16] = acc[i][c][q];
                }
            }
    }
}

// ---------------- SpMM: out[d] = dinv[d]*(sum Z[src] + Z[d]) + bias ----
// Z is bf16 [NN][128], pre-scaled by dinv[src]. Wave per node; lane owns
// channels (2l, 2l+1) = one u32. fp32 accumulate. 256 B contiguous per row gather.
// Row range = [rowstart, rowstart + deg - 1).

__global__ __launch_bounds__(256)
void k_spmm(const unsigned short* __restrict__ Z, const int* __restrict__ col,
            const int* __restrict__ rs, const int* __restrict__ deg,
            const float* __restrict__ dinv, const float* __restrict__ bias,
            float* __restrict__ out, int dorelu)
{
    int gid  = blockIdx.x * blockDim.x + threadIdx.x;
    int node = gid >> 6;
    int lane = threadIdx.x & 63;
    if (node >= NN) return;

    const int beg = rs[node];
    const int end = beg + deg[node] - 1;
    const float di = dinv[node];

    float ax, ay;
    {   // self loop: Z[d] already = dinv[d]*Y[d]
        const unsigned int u = *(const unsigned int*)(Z + (size_t)node * HH + lane * 2);
        ax = __uint_as_float(u << 16);
        ay = __uint_as_float(u & 0xffff0000u);
    }

    int e = beg;
    const int e8 = beg + ((end - beg) & ~7);
    for (; e < e8; e += 8) {
        int s[8];
#pragma unroll
        for (int q = 0; q < 8; ++q) s[q] = col[e + q];
        unsigned int v[8];
#pragma unroll
        for (int q = 0; q < 8; ++q)
            v[q] = *(const unsigned int*)(Z + (size_t)s[q] * HH + lane * 2);
#pragma unroll
        for (int q = 0; q < 8; ++q) {
            ax += __uint_as_float(v[q] << 16);
            ay += __uint_as_float(v[q] & 0xffff0000u);
        }
    }
    for (; e < end; ++e) {
        const unsigned int u = *(const unsigned int*)(Z + (size_t)col[e] * HH + lane * 2);
        ax += __uint_as_float(u << 16);
        ay += __uint_as_float(u & 0xffff0000u);
    }

    float ox = fmaf(di, ax, bias[lane * 2]);
    float oy = fmaf(di, ay, bias[lane * 2 + 1]);
    if (dorelu) { ox = fmaxf(ox, 0.f); oy = fmaxf(oy, 0.f); }
    float2 o; o.x = ox; o.y = oy;
    *(float2*)(out + (size_t)node * HH + lane * 2) = o;
}

// ---------------- launch ----------------

extern "C" void kernel_launch(void* const* d_in, const int* in_sizes, int n_in,
                              void* d_out, int out_size, void* d_ws, size_t ws_size,
                              hipStream_t stream)
{
    const int*   ei    = (const int*)d_in[0];
    const float* ext   = (const float*)d_in[1];
    const float* emb   = (const float*)d_in[2];
    const float* encW  = (const float*)d_in[3];
    const float* encB  = (const float*)d_in[4];
    const float* lng   = (const float*)d_in[5];
    const float* lnb   = (const float*)d_in[6];
    const float* projW = (const float*)d_in[7];
    const float* projB = (const float*)d_in[8];
    const float* W0    = (const float*)d_in[9];
    const float* b0    = (const float*)d_in[10];
    const float* W1    = (const float*)d_in[11];
    const float* b1    = (const float*)d_in[12];
    const float* W2    = (const float*)d_in[13];
    const float* b2    = (const float*)d_in[14];

    const int* srcI = ei;        // edge_index[0]
    const int* dstI = ei + EE;   // edge_index[1]

    char* w = (char*)d_ws;
    size_t off = 0;
    auto alloc = [&](size_t bytes) -> void* {
        void* p = w + off;
        off += (bytes + 255) & ~(size_t)255;
        return p;
    };
    int*   deg      = (int*)alloc((size_t)NN * 4);
    float* dinv     = (float*)alloc((size_t)NN * 4);
    int*   rowstart = (int*)alloc((size_t)NN * 4);
    int*   counter  = (int*)alloc(256);
    int*   lidx     = (int*)alloc((size_t)EE * 4);
    int*   col      = (int*)alloc((size_t)EE * 4);
    float* bufX     = (float*)alloc((size_t)NN * HH * 4);   // fp32 x / feat
    float* bufF     = (float*)alloc((size_t)NN * HH * 4);   // fp32 feat (GEMM1 out)
    unsigned short* bufZ = (unsigned short*)alloc((size_t)NN * HH * 2);  // bf16 Z
    // hi/lo fragment-layout weights: K*128*2 shorts = K*512 bytes
    short* wfE = (short*)alloc((size_t)768 * 512);
    short* wfP = (short*)alloc((size_t)256 * 512);
    short* wf0 = (short*)alloc((size_t)128 * 512);
    short* wf1 = (short*)alloc((size_t)128 * 512);
    short* wf2 = (short*)alloc((size_t)128 * 512);

    const int gN = (NN + 255) / 256;
    const int gE = (EE + 255) / 256;
    const int gG = (NN + 127) / 128;   // 128 rows per block
    const int gS = (NN + 3) / 4;       // 4 waves (nodes) per 256-thread block
    const int gW = (22528 + 255) / 256;

    k_wconv  <<<gW, 256, 0, stream>>>(encW, projW, W0, W1, W2, wfE, wfP, wf0, wf1, wf2);
    k_init   <<<gN, 256, 0, stream>>>(deg, counter);
    k_count  <<<gE, 256, 0, stream>>>(dstI, deg, lidx);
    k_offsets<<<gN, 256, 0, stream>>>(deg, dinv, rowstart, counter);
    k_fill   <<<gE, 256, 0, stream>>>(srcI, dstI, lidx, rowstart, col);

    // feat = relu(LN(ext @ encW + encB))                    -> bufF (f32)
    k_gemm<1, 0, 0><<<gG, 256, 0, stream>>>(ext, nullptr, wfE, encB, lng, lnb, nullptr, bufF, EXTD);
    // x = concat(emb, feat) @ projW + projB                 -> bufX (f32)
    k_gemm<0, 1, 0><<<gG, 256, 0, stream>>>(emb, bufF, wfP, projB, nullptr, nullptr, nullptr, bufX, 2 * HH);
    // Z0 = bf16(dinv .* (x @ W0))                           -> bufZ
    k_gemm<0, 0, 1><<<gG, 256, 0, stream>>>(bufX, nullptr, wf0, nullptr, nullptr, nullptr, dinv, bufZ, HH);
    // x = relu(dinv.*(sum Z0) + b0)                         -> bufX
    k_spmm<<<gS, 256, 0, stream>>>(bufZ, col, rowstart, deg, dinv, b0, bufX, 1);
    // Z1 = bf16(dinv .* (x @ W1))                           -> bufZ
    k_gemm<0, 0, 1><<<gG, 256, 0, stream>>>(bufX, nullptr, wf1, nullptr, nullptr, nullptr, dinv, bufZ, HH);
    // x = relu(dinv.*(sum Z1) + b1)                         -> bufX
    k_spmm<<<gS, 256, 0, stream>>>(bufZ, col, rowstart, deg, dinv, b1, bufX, 1);
    // Z2 = bf16(dinv .* (x @ W2))                           -> bufZ
    k_gemm<0, 0, 1><<<gG, 256, 0, stream>>>(bufX, nullptr, wf2, nullptr, nullptr, nullptr, dinv, bufZ, HH);
    // out = dinv.*(sum Z2) + b2                             -> d_out
    k_spmm<<<gS, 256, 0, stream>>>(bufZ, col, rowstart, deg, dinv, b2, (float*)d_out, 0);
}